// Round 5
// baseline (146.021 us; speedup 1.0000x reference)
//
#include <hip/hip_runtime.h>
#include <float.h>
#include <math.h>

// Problem constants (fixed by reference setup_inputs)
constexpr int NQ = 2048;    // queries
constexpr int ND = 65536;   // data points
constexpr int D  = 16;      // dims

// ---- MFMA-path tiling ----
// SCH=128: 1024 blocks = 4 blocks/CU = 4 waves/SIMD (TLP for latency hiding).
constexpr int SCH   = 128;          // point chunks
constexpr int CP    = ND / SCH;     // 512 points per chunk
constexpr int TPW   = CP / 32;      // 16 point-tiles (32 pts) per wave
constexpr int NPAIR = TPW / 2;      // 8 tile-pairs

typedef short bf16x8 __attribute__((ext_vector_type(8)));
typedef float f32x16 __attribute__((ext_vector_type(16)));

__device__ __forceinline__ unsigned short f2bf(float f) {  // RNE fp32->bf16
    unsigned u = __float_as_uint(f);
    u += 0x7FFFu + ((u >> 16) & 1u);
    return (unsigned short)(u >> 16);
}
__device__ __forceinline__ float bf2f(unsigned short h) {
    return __uint_as_float(((unsigned)h) << 16);
}

// ---------------------------------------------------------------------------
// Pack kernel (data only), MFMA-FRAGMENT-MAJOR layout:
//   Per 32-point tile t (2048 B = 1024 shorts):
//     [hi: lane 0..63 x 8 bf16][lo: lane 0..63 x 8 bf16]
//   where lane l consumes point (t*32 + (l&31)), elems (l>>5)*8 .. +8.
// XCD-SWIZZLED 1-D launch (256 blocks): the 2 blocks packing chunk cy run on
// XCD cy%8 (linear id % 8 == cy % 8), matching knn_mfma's placement — the
// packed chunk stays resident in that XCD's L2 (34 KiB/chunk, 16 chunks/XCD
// = 544 KiB of 4 MiB), so knn_mfma's B-loads are L2 hits.
//   nhf[ND] = -0.5*||p||^2 (fp32), tile-contiguous.
// ---------------------------------------------------------------------------
__global__ __launch_bounds__(256) void pack_data(const float* __restrict__ data,
                                                 unsigned short* __restrict__ Ppk,
                                                 float* __restrict__ nhf) {
    // Decode swizzled linear block id -> (chunk cy, half h):
    //   lb = (cy%8) + 8*(h + 2*(cy/8));  bijective over 256 blocks.
    const int lb  = blockIdx.x;
    const int xcd = lb & 7;
    const int r   = lb >> 3;       // [0,32)
    const int h2  = r & 1;         // half-chunk (256 pts)
    const int cg  = r >> 1;        // [0,16)
    const int cy  = xcd + 8 * cg;  // chunk [0,128)
    const int p   = cy * CP + h2 * 256 + threadIdx.x;

    const float4* r4 = (const float4*)(data + (size_t)p * D);
    float4 a = r4[0], b = r4[1], c = r4[2], e = r4[3];
    float v[16] = {a.x, a.y, a.z, a.w, b.x, b.y, b.z, b.w,
                   c.x, c.y, c.z, c.w, e.x, e.y, e.z, e.w};
    unsigned short hi[16], lo[16];
    float n = 0.f;
#pragma unroll
    for (int k = 0; k < 16; ++k) {
        n = fmaf(v[k], v[k], n);
        unsigned short h = f2bf(v[k]);
        hi[k] = h;
        lo[k] = f2bf(v[k] - bf2f(h));   // exact residual, rounded to bf16
    }
    const int t  = p >> 5;        // tile
    const int cc = p & 31;        // point-in-tile == output column == lane&31
    unsigned short* tb = Ppk + (size_t)t * 1024;
    const uint4* h4 = (const uint4*)hi;
    const uint4* l4 = (const uint4*)lo;
    *(uint4*)(tb +        cc * 8) = h4[0];   // hi, half 0 lane (cc)
    *(uint4*)(tb + 256 +  cc * 8) = h4[1];   // hi, half 1 lane (32+cc)
    *(uint4*)(tb + 512 +  cc * 8) = l4[0];   // lo, half 0
    *(uint4*)(tb + 768 +  cc * 8) = l4[1];   // lo, half 1
    nhf[p] = -0.5f * n;
}

// ---------------------------------------------------------------------------
// Main kernel: per wave, 64 queries (2 q-sets of 32) x one 512-point chunk.
//   best[q] = max_p ( x_q . p - 0.5*||p||^2 )   (argmin dist2 == argmax this)
// XCD-SWIZZLED 1-D launch (1024 blocks = 4 blocks/CU = 4 waves/SIMD): all 8
// q-slice blocks of chunk cy run on XCD cy%8 (chunk L2-resident after
// pack_data). SCH=128 doubles TLP vs the 512-block version: round-3/4
// counters showed the kernel latency-bound (MfmaUtil 8%, VALUBusy 18%,
// HBM 4%) at only 2 waves/SIMD — uncovered L2-hit latency on the 96
// B-loads/wave had no co-resident wave to fill the stall.
// B fragments loaded once per wave, reused by both q-sets. Per 32-pt tile per
// q-set: 3x mfma_f32_32x32x16_bf16 (hi*hi + lo*hi + hi*lo), C seeded with
// -0.5*||p||^2. Tile PAIRS with ping-pong prefetch; 4 independent accumulator
// chains. Epilogue per pair: 16x v_max3_f32 per q-set.
// C/D: col = lane&31, row = (reg&3) + 8*(reg>>2) + 4*(lane>>5)  [m74/m101].
// ---------------------------------------------------------------------------
__global__ __launch_bounds__(256, 4) void knn_mfma(const float* __restrict__ x,
                                                   const unsigned short* __restrict__ Ppk,
                                                   const float* __restrict__ nhf,
                                                   float* __restrict__ part) {
    // Decode swizzled linear block id -> (q-slice qx, chunk cy):
    //   lb = (cy%8) + 8*(qx + 8*(cy/8));  bijective over 1024 blocks.
    const int lb  = blockIdx.x;
    const int xcd = lb & 7;
    const int rr  = lb >> 3;       // [0,128)
    const int qx  = rr & 7;        // q-slice [0,8)
    const int cg  = rr >> 3;       // [0,16)
    const int cy  = xcd + 8 * cg;  // chunk [0,128)

    const int tid  = threadIdx.x;
    const int w    = tid >> 6;
    const int l    = tid & 63;
    const int half = l >> 5;
    const int n31  = l & 31;
    const int qbase = qx * 256 + w * 64;   // 4 waves x 64 queries
    const int pbase = cy * CP;

    // Build A fragments (hi/lo bf16) for both q-sets from raw fp32 x.
    bf16x8 axh0, axl0, axh1, axl1;
    {
        const float* xr0 = x + (size_t)(qbase + n31) * D + half * 8;
        float4 a0 = *(const float4*)xr0;
        float4 a1 = *(const float4*)(xr0 + 4);
        const float xv0[8] = {a0.x, a0.y, a0.z, a0.w, a1.x, a1.y, a1.z, a1.w};
#pragma unroll
        for (int k = 0; k < 8; ++k) {
            unsigned short h = f2bf(xv0[k]);
            axh0[k] = (short)h;
            axl0[k] = (short)f2bf(xv0[k] - bf2f(h));
        }
        const float* xr1 = x + (size_t)(qbase + 32 + n31) * D + half * 8;
        float4 b0 = *(const float4*)xr1;
        float4 b1 = *(const float4*)(xr1 + 4);
        const float xv1[8] = {b0.x, b0.y, b0.z, b0.w, b1.x, b1.y, b1.z, b1.w};
#pragma unroll
        for (int k = 0; k < 8; ++k) {
            unsigned short h = f2bf(xv1[k]);
            axh1[k] = (short)h;
            axl1[k] = (short)f2bf(xv1[k] - bf2f(h));
        }
    }

    // B-side pointers: fragment-major tiles, lane-contiguous.
    const unsigned short* bp = Ppk + (size_t)(pbase >> 5) * 1024 + l * 8;
    const float*          np = nhf + pbase + n31;
    // tile t: hi at bp + t*1024, lo at +512; nv at np + t*32

#define LDH(t) (*(const bf16x8*)(bp + (size_t)(t) * 1024))
#define LDL(t) (*(const bf16x8*)(bp + (size_t)(t) * 1024 + 512))
#define LDN(t) (np[(size_t)(t) * 32])

    f32x16 rbest0, rbest1;
#pragma unroll
    for (int r = 0; r < 16; ++r) { rbest0[r] = -FLT_MAX; rbest1[r] = -FLT_MAX; }

    auto compute_pair = [&](bf16x8 h0, bf16x8 l0, float n0,
                            bf16x8 h1, bf16x8 l1, float n1) {
        f32x16 c00, c01, c10, c11;   // c[qset][tile]
#pragma unroll
        for (int r = 0; r < 16; ++r) {
            c00[r] = n0; c01[r] = n1; c10[r] = n0; c11[r] = n1;
        }
        // 4 independent accumulator chains, 3 MFMAs deep each.
        c00 = __builtin_amdgcn_mfma_f32_32x32x16_bf16(axh0, h0, c00, 0, 0, 0);
        c01 = __builtin_amdgcn_mfma_f32_32x32x16_bf16(axh0, h1, c01, 0, 0, 0);
        c10 = __builtin_amdgcn_mfma_f32_32x32x16_bf16(axh1, h0, c10, 0, 0, 0);
        c11 = __builtin_amdgcn_mfma_f32_32x32x16_bf16(axh1, h1, c11, 0, 0, 0);
        c00 = __builtin_amdgcn_mfma_f32_32x32x16_bf16(axl0, h0, c00, 0, 0, 0);
        c01 = __builtin_amdgcn_mfma_f32_32x32x16_bf16(axl0, h1, c01, 0, 0, 0);
        c10 = __builtin_amdgcn_mfma_f32_32x32x16_bf16(axl1, h0, c10, 0, 0, 0);
        c11 = __builtin_amdgcn_mfma_f32_32x32x16_bf16(axl1, h1, c11, 0, 0, 0);
        c00 = __builtin_amdgcn_mfma_f32_32x32x16_bf16(axh0, l0, c00, 0, 0, 0);
        c01 = __builtin_amdgcn_mfma_f32_32x32x16_bf16(axh0, l1, c01, 0, 0, 0);
        c10 = __builtin_amdgcn_mfma_f32_32x32x16_bf16(axh1, l0, c10, 0, 0, 0);
        c11 = __builtin_amdgcn_mfma_f32_32x32x16_bf16(axh1, l1, c11, 0, 0, 0);
#pragma unroll
        for (int r = 0; r < 16; ++r) {
            rbest0[r] = fmaxf(rbest0[r], fmaxf(c00[r], c01[r]));  // -> v_max3_f32
            rbest1[r] = fmaxf(rbest1[r], fmaxf(c10[r], c11[r]));
        }
    };

    // Ping-pong over tile pairs: pair p = tiles {2p, 2p+1}
    bf16x8 Ah0 = LDH(0), Al0 = LDL(0), Ah1 = LDH(1), Al1 = LDL(1);
    float  An0 = LDN(0), An1 = LDN(1);
    bf16x8 Bh0, Bl0, Bh1, Bl1;
    float  Bn0, Bn1;

    for (int p = 0; p < NPAIR; p += 2) {
        const int tB = (p + 1) * 2;
        Bh0 = LDH(tB);     Bl0 = LDL(tB);     Bn0 = LDN(tB);
        Bh1 = LDH(tB + 1); Bl1 = LDL(tB + 1); Bn1 = LDN(tB + 1);
        compute_pair(Ah0, Al0, An0, Ah1, Al1, An1);
        if (p + 2 < NPAIR) {
            const int tA = (p + 2) * 2;
            Ah0 = LDH(tA);     Al0 = LDL(tA);     An0 = LDN(tA);
            Ah1 = LDH(tA + 1); Al1 = LDL(tA + 1); An1 = LDN(tA + 1);
        }
        compute_pair(Bh0, Bl0, Bn0, Bh1, Bl1, Bn1);
    }
#undef LDH
#undef LDL
#undef LDN

    // max over the 32 point-columns (lanes within each half)
#pragma unroll
    for (int r = 0; r < 16; ++r) {
        float v0 = rbest0[r];
        v0 = fmaxf(v0, __shfl_xor(v0, 1, 32));
        v0 = fmaxf(v0, __shfl_xor(v0, 2, 32));
        v0 = fmaxf(v0, __shfl_xor(v0, 4, 32));
        v0 = fmaxf(v0, __shfl_xor(v0, 8, 32));
        v0 = fmaxf(v0, __shfl_xor(v0, 16, 32));
        rbest0[r] = v0;
        float v1 = rbest1[r];
        v1 = fmaxf(v1, __shfl_xor(v1, 1, 32));
        v1 = fmaxf(v1, __shfl_xor(v1, 2, 32));
        v1 = fmaxf(v1, __shfl_xor(v1, 4, 32));
        v1 = fmaxf(v1, __shfl_xor(v1, 8, 32));
        v1 = fmaxf(v1, __shfl_xor(v1, 16, 32));
        rbest1[r] = v1;
    }
    if (n31 == 0) {
        float* pp = part + (size_t)cy * NQ + qbase + 4 * half;
#pragma unroll
        for (int r = 0; r < 16; ++r) pp[(r & 3) + 8 * (r >> 2)] = rbest0[r];
        pp += 32;
#pragma unroll
        for (int r = 0; r < 16; ++r) pp[(r & 3) + 8 * (r >> 2)] = rbest1[r];
    }
}

// ---------------------------------------------------------------------------
// Final: reduce SCH chunks, dist2 = ||x||^2 - 2*best, bump.
// Reads are lane-contiguous per chunk iteration (coalesced).
// ---------------------------------------------------------------------------
__global__ __launch_bounds__(256) void knn_final(const float* __restrict__ x,
                                                 const float* __restrict__ part,
                                                 float* __restrict__ out) {
    const int q = blockIdx.x * 256 + threadIdx.x;
    const float4* xr = (const float4*)(x + (size_t)q * D);
    float4 a = xr[0], b = xr[1], c = xr[2], e = xr[3];
    float x2 = a.x * a.x;
    x2 = fmaf(a.y, a.y, x2); x2 = fmaf(a.z, a.z, x2); x2 = fmaf(a.w, a.w, x2);
    x2 = fmaf(b.x, b.x, x2); x2 = fmaf(b.y, b.y, x2); x2 = fmaf(b.z, b.z, x2); x2 = fmaf(b.w, b.w, x2);
    x2 = fmaf(c.x, c.x, x2); x2 = fmaf(c.y, c.y, x2); x2 = fmaf(c.z, c.z, x2); x2 = fmaf(c.w, c.w, x2);
    x2 = fmaf(e.x, e.x, x2); x2 = fmaf(e.y, e.y, x2); x2 = fmaf(e.z, e.z, x2); x2 = fmaf(e.w, e.w, x2);

    float mbest = -FLT_MAX;
#pragma unroll
    for (int cI = 0; cI < SCH; ++cI) mbest = fmaxf(mbest, part[(size_t)cI * NQ + q]);

    float nn2  = fmaxf(fmaf(-2.f, mbest, x2), 0.f);
    float dist = sqrtf(fmaxf(nn2, 1e-12f));
    float bump = 0.f;
    if (dist < 2.0f) {                      // RADIUS = 2
        float denom = dist * dist - 4.0f;   // d^2 - r^2
        bump = expf(1.0f / denom + 0.25f);  // DECAY/denom + DECAY/r^2
    }
    out[q] = bump;
}

// ===========================================================================
// Fallback (fp32 scalar-pipe path) if workspace is too small for MFMA path.
// ===========================================================================
__global__ __launch_bounds__(256) void neg_half_norms(const float* __restrict__ data,
                                                      float* __restrict__ nhn) {
    const int p = blockIdx.x * 256 + threadIdx.x;
    const float4* r = (const float4*)(data + (size_t)p * D);
    float4 a = r[0], b = r[1], c = r[2], e = r[3];
    float n = a.x * a.x;
    n = fmaf(a.y, a.y, n); n = fmaf(a.z, a.z, n); n = fmaf(a.w, a.w, n);
    n = fmaf(b.x, b.x, n); n = fmaf(b.y, b.y, n); n = fmaf(b.z, b.z, n); n = fmaf(b.w, b.w, n);
    n = fmaf(c.x, c.x, n); n = fmaf(c.y, c.y, n); n = fmaf(c.z, c.z, n); n = fmaf(c.w, c.w, n);
    n = fmaf(e.x, e.x, n); n = fmaf(e.y, e.y, n); n = fmaf(e.z, e.z, n); n = fmaf(e.w, e.w, n);
    nhn[p] = -0.5f * n;
}

__global__ __launch_bounds__(256) void knn_partial_fb(const float* __restrict__ x,
                                                      const float* __restrict__ data,
                                                      const float* __restrict__ nhn,
                                                      float* __restrict__ part, int cp) {
    const int q     = blockIdx.x * 256 + threadIdx.x;
    const int pbase = blockIdx.y * cp;
    const float4* xr = (const float4*)(x + (size_t)q * D);
    const float4 xa = xr[0], xb = xr[1], xc = xr[2], xd = xr[3];
    const float* dp = data + (size_t)pbase * D;
    const float* np = nhn + pbase;
    float best = -FLT_MAX;
    for (int i = 0; i < cp; i += 4) {
#pragma unroll
        for (int j = 0; j < 4; ++j) {
            const float* r  = dp + (size_t)(i + j) * D;
            const float  hn = np[i + j];
            float ca = xa.x * r[0];
            ca = fmaf(xa.y, r[1], ca);  ca = fmaf(xa.z, r[2], ca);  ca = fmaf(xa.w, r[3], ca);
            ca = fmaf(xb.x, r[4], ca);  ca = fmaf(xb.y, r[5], ca);  ca = fmaf(xb.z, r[6], ca);
            ca = fmaf(xb.w, r[7], ca);
            float cb = fmaf(xc.x, r[8], hn);
            cb = fmaf(xc.y, r[9],  cb); cb = fmaf(xc.z, r[10], cb); cb = fmaf(xc.w, r[11], cb);
            cb = fmaf(xd.x, r[12], cb); cb = fmaf(xd.y, r[13], cb); cb = fmaf(xd.z, r[14], cb);
            cb = fmaf(xd.w, r[15], cb);
            best = fmaxf(best, ca + cb);
        }
    }
    part[(size_t)blockIdx.y * NQ + q] = best;
}

__global__ __launch_bounds__(256) void knn_final_fb(const float* __restrict__ x,
                                                    const float* __restrict__ part,
                                                    float* __restrict__ out, int S) {
    const int q = blockIdx.x * 256 + threadIdx.x;
    const float4* xr = (const float4*)(x + (size_t)q * D);
    float4 a = xr[0], b = xr[1], c = xr[2], e = xr[3];
    float x2 = a.x * a.x;
    x2 = fmaf(a.y, a.y, x2); x2 = fmaf(a.z, a.z, x2); x2 = fmaf(a.w, a.w, x2);
    x2 = fmaf(b.x, b.x, x2); x2 = fmaf(b.y, b.y, x2); x2 = fmaf(b.z, b.z, x2); x2 = fmaf(b.w, b.w, x2);
    x2 = fmaf(c.x, c.x, x2); x2 = fmaf(c.y, c.y, x2); x2 = fmaf(c.z, c.z, x2); x2 = fmaf(c.w, c.w, x2);
    x2 = fmaf(e.x, e.x, x2); x2 = fmaf(e.y, e.y, x2); x2 = fmaf(e.z, e.z, x2); x2 = fmaf(e.w, e.w, x2);
    float mb = -FLT_MAX;
    for (int cI = 0; cI < S; ++cI) mb = fmaxf(mb, part[(size_t)cI * NQ + q]);
    float nn2  = fmaxf(fmaf(-2.f, mb, x2), 0.f);
    float dist = sqrtf(fmaxf(nn2, 1e-12f));
    float bump = 0.f;
    if (dist < 2.0f) {
        float denom = dist * dist - 4.0f;
        bump = expf(1.0f / denom + 0.25f);
    }
    out[q] = bump;
}

extern "C" void kernel_launch(void* const* d_in, const int* in_sizes, int n_in,
                              void* d_out, int out_size, void* d_ws, size_t ws_size,
                              hipStream_t stream) {
    const float* x    = (const float*)d_in[0];   // [2048,16] fp32
    const float* data = (const float*)d_in[1];   // [65536,16] fp32
    float* out = (float*)d_out;                  // [2048] fp32

    // ws layout (bytes):
    //   Ppk  [0, 4 MiB)          ND/32 tiles * 1024 shorts (fragment-major)
    //   nhf  [4 MiB, +256 KiB)   ND fp32
    //   part [+1 MiB)            SCH*NQ fp32
    const size_t off_nhf  = (size_t)ND * 32 * 2;             // 4194304
    const size_t off_part = off_nhf + (size_t)ND * 4;        // 4456448
    const size_t needed   = off_part + (size_t)SCH * NQ * 4; // 5505024

    if (ws_size >= needed) {
        unsigned short* Ppk = (unsigned short*)d_ws;
        float* nhf  = (float*)((char*)d_ws + off_nhf);
        float* part = (float*)((char*)d_ws + off_part);

        pack_data<<<ND / 256, 256, 0, stream>>>(data, Ppk, nhf);
        knn_mfma<<<8 * SCH, 256, 0, stream>>>(x, Ppk, nhf, part);
        knn_final<<<NQ / 256, 256, 0, stream>>>(x, part, out);
    } else {
        int S = 32;
        while (S > 1 && (size_t)(ND + S * NQ) * sizeof(float) > ws_size) S >>= 1;
        const int cp = ND / S;
        float* nhn  = (float*)d_ws;
        float* part = (float*)d_ws + ND;
        neg_half_norms<<<ND / 256, 256, 0, stream>>>(data, nhn);
        knn_partial_fb<<<dim3(NQ / 256, S), 256, 0, stream>>>(x, data, nhn, part, cp);
        knn_final_fb<<<NQ / 256, 256, 0, stream>>>(x, part, out, S);
    }
}

// Round 6
// 84.012 us; speedup vs baseline: 1.7381x; 1.7381x over previous
//
#include <hip/hip_runtime.h>
#include <float.h>
#include <math.h>

// Problem constants (fixed by reference setup_inputs)
constexpr int NQ = 2048;    // queries
constexpr int ND = 65536;   // data points
constexpr int D  = 16;      // dims

// ---- MFMA-path tiling ----
// SCH=128: 1024 blocks = 4 blocks/CU = 4 waves/SIMD (TLP for latency hiding).
constexpr int SCH   = 128;          // point chunks
constexpr int CP    = ND / SCH;     // 512 points per chunk
constexpr int TPW   = CP / 32;      // 16 point-tiles (32 pts) per wave
constexpr int NPAIR = TPW / 2;      // 8 tile-pairs

typedef short bf16x8 __attribute__((ext_vector_type(8)));
typedef float f32x16 __attribute__((ext_vector_type(16)));

__device__ __forceinline__ unsigned short f2bf(float f) {  // RNE fp32->bf16
    unsigned u = __float_as_uint(f);
    u += 0x7FFFu + ((u >> 16) & 1u);
    return (unsigned short)(u >> 16);
}
__device__ __forceinline__ float bf2f(unsigned short h) {
    return __uint_as_float(((unsigned)h) << 16);
}

// ---------------------------------------------------------------------------
// Pack kernel (data only), MFMA-FRAGMENT-MAJOR layout:
//   Per 32-point tile t (2048 B = 1024 shorts):
//     [hi: lane 0..63 x 8 bf16][lo: lane 0..63 x 8 bf16]
//   where lane l consumes point (t*32 + (l&31)), elems (l>>5)*8 .. +8.
// XCD-SWIZZLED 1-D launch (256 blocks): the 2 blocks packing chunk cy run on
// XCD cy%8 (linear id % 8 == cy % 8), matching knn_mfma's placement — the
// packed chunk stays resident in that XCD's L2 (34 KiB/chunk, 16 chunks/XCD
// = 544 KiB of 4 MiB), so knn_mfma's B-loads are L2 hits.
//   nhf[ND] = -0.5*||p||^2 (fp32), tile-contiguous.
// ---------------------------------------------------------------------------
__global__ __launch_bounds__(256) void pack_data(const float* __restrict__ data,
                                                 unsigned short* __restrict__ Ppk,
                                                 float* __restrict__ nhf) {
    // Decode swizzled linear block id -> (chunk cy, half h):
    //   lb = (cy%8) + 8*(h + 2*(cy/8));  bijective over 256 blocks.
    const int lb  = blockIdx.x;
    const int xcd = lb & 7;
    const int r   = lb >> 3;       // [0,32)
    const int h2  = r & 1;         // half-chunk (256 pts)
    const int cg  = r >> 1;        // [0,16)
    const int cy  = xcd + 8 * cg;  // chunk [0,128)
    const int p   = cy * CP + h2 * 256 + threadIdx.x;

    const float4* r4 = (const float4*)(data + (size_t)p * D);
    float4 a = r4[0], b = r4[1], c = r4[2], e = r4[3];
    float v[16] = {a.x, a.y, a.z, a.w, b.x, b.y, b.z, b.w,
                   c.x, c.y, c.z, c.w, e.x, e.y, e.z, e.w};
    unsigned short hi[16], lo[16];
    float n = 0.f;
#pragma unroll
    for (int k = 0; k < 16; ++k) {
        n = fmaf(v[k], v[k], n);
        unsigned short h = f2bf(v[k]);
        hi[k] = h;
        lo[k] = f2bf(v[k] - bf2f(h));   // exact residual, rounded to bf16
    }
    const int t  = p >> 5;        // tile
    const int cc = p & 31;        // point-in-tile == output column == lane&31
    unsigned short* tb = Ppk + (size_t)t * 1024;
    const uint4* h4 = (const uint4*)hi;
    const uint4* l4 = (const uint4*)lo;
    *(uint4*)(tb +        cc * 8) = h4[0];   // hi, half 0 lane (cc)
    *(uint4*)(tb + 256 +  cc * 8) = h4[1];   // hi, half 1 lane (32+cc)
    *(uint4*)(tb + 512 +  cc * 8) = l4[0];   // lo, half 0
    *(uint4*)(tb + 768 +  cc * 8) = l4[1];   // lo, half 1
    nhf[p] = -0.5f * n;
}

// ---------------------------------------------------------------------------
// Main kernel: per wave, 64 queries (2 q-sets of 32) x one 512-point chunk.
//   best[q] = max_p ( x_q . p - 0.5*||p||^2 )   (argmin dist2 == argmax this)
// XCD-SWIZZLED 1-D launch, 1024 blocks. IMPORTANT: __launch_bounds__(256, 2)
// — NOT (256, 4). Round-5 measured that min-waves=4 forced the allocator to
// a 64-VGPR budget (kernel needs ~108 live: 4x f32x16 acc + 2x rbest +
// frags) -> scratch spill -> 350 MB/dispatch HBM traffic -> 87 us. With
// VGPR=108 <= 128, HW occupancy is already 16 waves/CU (m69), so the
// 1024-block grid gives 4 blocks/CU = 4 waves/SIMD WITHOUT constraining the
// allocator. All 8 q-slice blocks of chunk cy run on XCD cy%8 (chunk
// L2-resident after pack_data).
// B fragments loaded once per wave, reused by both q-sets. Per 32-pt tile per
// q-set: 3x mfma_f32_32x32x16_bf16 (hi*hi + lo*hi + hi*lo), C seeded with
// -0.5*||p||^2. Tile PAIRS with ping-pong prefetch; 4 independent accumulator
// chains. Epilogue per pair: 16x v_max3_f32 per q-set.
// C/D: col = lane&31, row = (reg&3) + 8*(reg>>2) + 4*(lane>>5)  [m74/m101].
// ---------------------------------------------------------------------------
__global__ __launch_bounds__(256, 2) void knn_mfma(const float* __restrict__ x,
                                                   const unsigned short* __restrict__ Ppk,
                                                   const float* __restrict__ nhf,
                                                   float* __restrict__ part) {
    // Decode swizzled linear block id -> (q-slice qx, chunk cy):
    //   lb = (cy%8) + 8*(qx + 8*(cy/8));  bijective over 1024 blocks.
    const int lb  = blockIdx.x;
    const int xcd = lb & 7;
    const int rr  = lb >> 3;       // [0,128)
    const int qx  = rr & 7;        // q-slice [0,8)
    const int cg  = rr >> 3;       // [0,16)
    const int cy  = xcd + 8 * cg;  // chunk [0,128)

    const int tid  = threadIdx.x;
    const int w    = tid >> 6;
    const int l    = tid & 63;
    const int half = l >> 5;
    const int n31  = l & 31;
    const int qbase = qx * 256 + w * 64;   // 4 waves x 64 queries
    const int pbase = cy * CP;

    // Build A fragments (hi/lo bf16) for both q-sets from raw fp32 x.
    bf16x8 axh0, axl0, axh1, axl1;
    {
        const float* xr0 = x + (size_t)(qbase + n31) * D + half * 8;
        float4 a0 = *(const float4*)xr0;
        float4 a1 = *(const float4*)(xr0 + 4);
        const float xv0[8] = {a0.x, a0.y, a0.z, a0.w, a1.x, a1.y, a1.z, a1.w};
#pragma unroll
        for (int k = 0; k < 8; ++k) {
            unsigned short h = f2bf(xv0[k]);
            axh0[k] = (short)h;
            axl0[k] = (short)f2bf(xv0[k] - bf2f(h));
        }
        const float* xr1 = x + (size_t)(qbase + 32 + n31) * D + half * 8;
        float4 b0 = *(const float4*)xr1;
        float4 b1 = *(const float4*)(xr1 + 4);
        const float xv1[8] = {b0.x, b0.y, b0.z, b0.w, b1.x, b1.y, b1.z, b1.w};
#pragma unroll
        for (int k = 0; k < 8; ++k) {
            unsigned short h = f2bf(xv1[k]);
            axh1[k] = (short)h;
            axl1[k] = (short)f2bf(xv1[k] - bf2f(h));
        }
    }

    // B-side pointers: fragment-major tiles, lane-contiguous.
    const unsigned short* bp = Ppk + (size_t)(pbase >> 5) * 1024 + l * 8;
    const float*          np = nhf + pbase + n31;
    // tile t: hi at bp + t*1024, lo at +512; nv at np + t*32

#define LDH(t) (*(const bf16x8*)(bp + (size_t)(t) * 1024))
#define LDL(t) (*(const bf16x8*)(bp + (size_t)(t) * 1024 + 512))
#define LDN(t) (np[(size_t)(t) * 32])

    f32x16 rbest0, rbest1;
#pragma unroll
    for (int r = 0; r < 16; ++r) { rbest0[r] = -FLT_MAX; rbest1[r] = -FLT_MAX; }

    auto compute_pair = [&](bf16x8 h0, bf16x8 l0, float n0,
                            bf16x8 h1, bf16x8 l1, float n1) {
        f32x16 c00, c01, c10, c11;   // c[qset][tile]
#pragma unroll
        for (int r = 0; r < 16; ++r) {
            c00[r] = n0; c01[r] = n1; c10[r] = n0; c11[r] = n1;
        }
        // 4 independent accumulator chains, 3 MFMAs deep each.
        c00 = __builtin_amdgcn_mfma_f32_32x32x16_bf16(axh0, h0, c00, 0, 0, 0);
        c01 = __builtin_amdgcn_mfma_f32_32x32x16_bf16(axh0, h1, c01, 0, 0, 0);
        c10 = __builtin_amdgcn_mfma_f32_32x32x16_bf16(axh1, h0, c10, 0, 0, 0);
        c11 = __builtin_amdgcn_mfma_f32_32x32x16_bf16(axh1, h1, c11, 0, 0, 0);
        c00 = __builtin_amdgcn_mfma_f32_32x32x16_bf16(axl0, h0, c00, 0, 0, 0);
        c01 = __builtin_amdgcn_mfma_f32_32x32x16_bf16(axl0, h1, c01, 0, 0, 0);
        c10 = __builtin_amdgcn_mfma_f32_32x32x16_bf16(axl1, h0, c10, 0, 0, 0);
        c11 = __builtin_amdgcn_mfma_f32_32x32x16_bf16(axl1, h1, c11, 0, 0, 0);
        c00 = __builtin_amdgcn_mfma_f32_32x32x16_bf16(axh0, l0, c00, 0, 0, 0);
        c01 = __builtin_amdgcn_mfma_f32_32x32x16_bf16(axh0, l1, c01, 0, 0, 0);
        c10 = __builtin_amdgcn_mfma_f32_32x32x16_bf16(axh1, l0, c10, 0, 0, 0);
        c11 = __builtin_amdgcn_mfma_f32_32x32x16_bf16(axh1, l1, c11, 0, 0, 0);
#pragma unroll
        for (int r = 0; r < 16; ++r) {
            rbest0[r] = fmaxf(rbest0[r], fmaxf(c00[r], c01[r]));  // -> v_max3_f32
            rbest1[r] = fmaxf(rbest1[r], fmaxf(c10[r], c11[r]));
        }
    };

    // Ping-pong over tile pairs: pair p = tiles {2p, 2p+1}
    bf16x8 Ah0 = LDH(0), Al0 = LDL(0), Ah1 = LDH(1), Al1 = LDL(1);
    float  An0 = LDN(0), An1 = LDN(1);
    bf16x8 Bh0, Bl0, Bh1, Bl1;
    float  Bn0, Bn1;

    for (int p = 0; p < NPAIR; p += 2) {
        const int tB = (p + 1) * 2;
        Bh0 = LDH(tB);     Bl0 = LDL(tB);     Bn0 = LDN(tB);
        Bh1 = LDH(tB + 1); Bl1 = LDL(tB + 1); Bn1 = LDN(tB + 1);
        compute_pair(Ah0, Al0, An0, Ah1, Al1, An1);
        if (p + 2 < NPAIR) {
            const int tA = (p + 2) * 2;
            Ah0 = LDH(tA);     Al0 = LDL(tA);     An0 = LDN(tA);
            Ah1 = LDH(tA + 1); Al1 = LDL(tA + 1); An1 = LDN(tA + 1);
        }
        compute_pair(Bh0, Bl0, Bn0, Bh1, Bl1, Bn1);
    }
#undef LDH
#undef LDL
#undef LDN

    // max over the 32 point-columns (lanes within each half)
#pragma unroll
    for (int r = 0; r < 16; ++r) {
        float v0 = rbest0[r];
        v0 = fmaxf(v0, __shfl_xor(v0, 1, 32));
        v0 = fmaxf(v0, __shfl_xor(v0, 2, 32));
        v0 = fmaxf(v0, __shfl_xor(v0, 4, 32));
        v0 = fmaxf(v0, __shfl_xor(v0, 8, 32));
        v0 = fmaxf(v0, __shfl_xor(v0, 16, 32));
        rbest0[r] = v0;
        float v1 = rbest1[r];
        v1 = fmaxf(v1, __shfl_xor(v1, 1, 32));
        v1 = fmaxf(v1, __shfl_xor(v1, 2, 32));
        v1 = fmaxf(v1, __shfl_xor(v1, 4, 32));
        v1 = fmaxf(v1, __shfl_xor(v1, 8, 32));
        v1 = fmaxf(v1, __shfl_xor(v1, 16, 32));
        rbest1[r] = v1;
    }
    if (n31 == 0) {
        float* pp = part + (size_t)cy * NQ + qbase + 4 * half;
#pragma unroll
        for (int r = 0; r < 16; ++r) pp[(r & 3) + 8 * (r >> 2)] = rbest0[r];
        pp += 32;
#pragma unroll
        for (int r = 0; r < 16; ++r) pp[(r & 3) + 8 * (r >> 2)] = rbest1[r];
    }
}

// ---------------------------------------------------------------------------
// Final: reduce SCH chunks, dist2 = ||x||^2 - 2*best, bump.
// Reads are lane-contiguous per chunk iteration (coalesced).
// ---------------------------------------------------------------------------
__global__ __launch_bounds__(256) void knn_final(const float* __restrict__ x,
                                                 const float* __restrict__ part,
                                                 float* __restrict__ out) {
    const int q = blockIdx.x * 256 + threadIdx.x;
    const float4* xr = (const float4*)(x + (size_t)q * D);
    float4 a = xr[0], b = xr[1], c = xr[2], e = xr[3];
    float x2 = a.x * a.x;
    x2 = fmaf(a.y, a.y, x2); x2 = fmaf(a.z, a.z, x2); x2 = fmaf(a.w, a.w, x2);
    x2 = fmaf(b.x, b.x, x2); x2 = fmaf(b.y, b.y, x2); x2 = fmaf(b.z, b.z, x2); x2 = fmaf(b.w, b.w, x2);
    x2 = fmaf(c.x, c.x, x2); x2 = fmaf(c.y, c.y, x2); x2 = fmaf(c.z, c.z, x2); x2 = fmaf(c.w, c.w, x2);
    x2 = fmaf(e.x, e.x, x2); x2 = fmaf(e.y, e.y, x2); x2 = fmaf(e.z, e.z, x2); x2 = fmaf(e.w, e.w, x2);

    float mbest = -FLT_MAX;
#pragma unroll
    for (int cI = 0; cI < SCH; ++cI) mbest = fmaxf(mbest, part[(size_t)cI * NQ + q]);

    float nn2  = fmaxf(fmaf(-2.f, mbest, x2), 0.f);
    float dist = sqrtf(fmaxf(nn2, 1e-12f));
    float bump = 0.f;
    if (dist < 2.0f) {                      // RADIUS = 2
        float denom = dist * dist - 4.0f;   // d^2 - r^2
        bump = expf(1.0f / denom + 0.25f);  // DECAY/denom + DECAY/r^2
    }
    out[q] = bump;
}

// ===========================================================================
// Fallback (fp32 scalar-pipe path) if workspace is too small for MFMA path.
// ===========================================================================
__global__ __launch_bounds__(256) void neg_half_norms(const float* __restrict__ data,
                                                      float* __restrict__ nhn) {
    const int p = blockIdx.x * 256 + threadIdx.x;
    const float4* r = (const float4*)(data + (size_t)p * D);
    float4 a = r[0], b = r[1], c = r[2], e = r[3];
    float n = a.x * a.x;
    n = fmaf(a.y, a.y, n); n = fmaf(a.z, a.z, n); n = fmaf(a.w, a.w, n);
    n = fmaf(b.x, b.x, n); n = fmaf(b.y, b.y, n); n = fmaf(b.z, b.z, n); n = fmaf(b.w, b.w, n);
    n = fmaf(c.x, c.x, n); n = fmaf(c.y, c.y, n); n = fmaf(c.z, c.z, n); n = fmaf(c.w, c.w, n);
    n = fmaf(e.x, e.x, n); n = fmaf(e.y, e.y, n); n = fmaf(e.z, e.z, n); n = fmaf(e.w, e.w, n);
    nhn[p] = -0.5f * n;
}

__global__ __launch_bounds__(256) void knn_partial_fb(const float* __restrict__ x,
                                                      const float* __restrict__ data,
                                                      const float* __restrict__ nhn,
                                                      float* __restrict__ part, int cp) {
    const int q     = blockIdx.x * 256 + threadIdx.x;
    const int pbase = blockIdx.y * cp;
    const float4* xr = (const float4*)(x + (size_t)q * D);
    const float4 xa = xr[0], xb = xr[1], xc = xr[2], xd = xr[3];
    const float* dp = data + (size_t)pbase * D;
    const float* np = nhn + pbase;
    float best = -FLT_MAX;
    for (int i = 0; i < cp; i += 4) {
#pragma unroll
        for (int j = 0; j < 4; ++j) {
            const float* r  = dp + (size_t)(i + j) * D;
            const float  hn = np[i + j];
            float ca = xa.x * r[0];
            ca = fmaf(xa.y, r[1], ca);  ca = fmaf(xa.z, r[2], ca);  ca = fmaf(xa.w, r[3], ca);
            ca = fmaf(xb.x, r[4], ca);  ca = fmaf(xb.y, r[5], ca);  ca = fmaf(xb.z, r[6], ca);
            ca = fmaf(xb.w, r[7], ca);
            float cb = fmaf(xc.x, r[8], hn);
            cb = fmaf(xc.y, r[9],  cb); cb = fmaf(xc.z, r[10], cb); cb = fmaf(xc.w, r[11], cb);
            cb = fmaf(xd.x, r[12], cb); cb = fmaf(xd.y, r[13], cb); cb = fmaf(xd.z, r[14], cb);
            cb = fmaf(xd.w, r[15], cb);
            best = fmaxf(best, ca + cb);
        }
    }
    part[(size_t)blockIdx.y * NQ + q] = best;
}

__global__ __launch_bounds__(256) void knn_final_fb(const float* __restrict__ x,
                                                    const float* __restrict__ part,
                                                    float* __restrict__ out, int S) {
    const int q = blockIdx.x * 256 + threadIdx.x;
    const float4* xr = (const float4*)(x + (size_t)q * D);
    float4 a = xr[0], b = xr[1], c = xr[2], e = xr[3];
    float x2 = a.x * a.x;
    x2 = fmaf(a.y, a.y, x2); x2 = fmaf(a.z, a.z, x2); x2 = fmaf(a.w, a.w, x2);
    x2 = fmaf(b.x, b.x, x2); x2 = fmaf(b.y, b.y, x2); x2 = fmaf(b.z, b.z, x2); x2 = fmaf(b.w, b.w, x2);
    x2 = fmaf(c.x, c.x, x2); x2 = fmaf(c.y, c.y, x2); x2 = fmaf(c.z, c.z, x2); x2 = fmaf(c.w, c.w, x2);
    x2 = fmaf(e.x, e.x, x2); x2 = fmaf(e.y, e.y, x2); x2 = fmaf(e.z, e.z, x2); x2 = fmaf(e.w, e.w, x2);
    float mb = -FLT_MAX;
    for (int cI = 0; cI < S; ++cI) mb = fmaxf(mb, part[(size_t)cI * NQ + q]);
    float nn2  = fmaxf(fmaf(-2.f, mb, x2), 0.f);
    float dist = sqrtf(fmaxf(nn2, 1e-12f));
    float bump = 0.f;
    if (dist < 2.0f) {
        float denom = dist * dist - 4.0f;
        bump = expf(1.0f / denom + 0.25f);
    }
    out[q] = bump;
}

extern "C" void kernel_launch(void* const* d_in, const int* in_sizes, int n_in,
                              void* d_out, int out_size, void* d_ws, size_t ws_size,
                              hipStream_t stream) {
    const float* x    = (const float*)d_in[0];   // [2048,16] fp32
    const float* data = (const float*)d_in[1];   // [65536,16] fp32
    float* out = (float*)d_out;                  // [2048] fp32

    // ws layout (bytes):
    //   Ppk  [0, 4 MiB)          ND/32 tiles * 1024 shorts (fragment-major)
    //   nhf  [4 MiB, +256 KiB)   ND fp32
    //   part [+1 MiB)            SCH*NQ fp32
    const size_t off_nhf  = (size_t)ND * 32 * 2;             // 4194304
    const size_t off_part = off_nhf + (size_t)ND * 4;        // 4456448
    const size_t needed   = off_part + (size_t)SCH * NQ * 4; // 5505024

    if (ws_size >= needed) {
        unsigned short* Ppk = (unsigned short*)d_ws;
        float* nhf  = (float*)((char*)d_ws + off_nhf);
        float* part = (float*)((char*)d_ws + off_part);

        pack_data<<<ND / 256, 256, 0, stream>>>(data, Ppk, nhf);
        knn_mfma<<<8 * SCH, 256, 0, stream>>>(x, Ppk, nhf, part);
        knn_final<<<NQ / 256, 256, 0, stream>>>(x, part, out);
    } else {
        int S = 32;
        while (S > 1 && (size_t)(ND + S * NQ) * sizeof(float) > ws_size) S >>= 1;
        const int cp = ND / S;
        float* nhn  = (float*)d_ws;
        float* part = (float*)d_ws + ND;
        neg_half_norms<<<ND / 256, 256, 0, stream>>>(data, nhn);
        knn_partial_fb<<<dim3(NQ / 256, S), 256, 0, stream>>>(x, data, nhn, part, cp);
        knn_final_fb<<<NQ / 256, 256, 0, stream>>>(x, part, out, S);
    }
}

// Round 8
// 75.985 us; speedup vs baseline: 1.9217x; 1.1056x over previous
//
#include <hip/hip_runtime.h>
#include <float.h>
#include <math.h>

// Problem constants (fixed by reference setup_inputs)
constexpr int NQ = 2048;    // queries
constexpr int ND = 65536;   // data points
constexpr int D  = 16;      // dims

// ---- MFMA-path tiling (R4 config: best measured) ----
constexpr int SCH   = 64;           // point chunks
constexpr int CP    = ND / SCH;     // 1024 points per chunk
constexpr int TPW   = CP / 32;      // 32 point-tiles (32 pts) per wave

typedef short bf16x8 __attribute__((ext_vector_type(8)));
typedef float f32x16 __attribute__((ext_vector_type(16)));

__device__ __forceinline__ unsigned short f2bf(float f) {  // RNE fp32->bf16
    unsigned u = __float_as_uint(f);
    u += 0x7FFFu + ((u >> 16) & 1u);
    return (unsigned short)(u >> 16);
}
__device__ __forceinline__ float bf2f(unsigned short h) {
    return __uint_as_float(((unsigned)h) << 16);
}

// ---------------------------------------------------------------------------
// Pack kernel (data only), MFMA-FRAGMENT-MAJOR layout:
//   Per 32-point tile t (2048 B = 1024 shorts):
//     [hi: lane 0..63 x 8 bf16][lo: lane 0..63 x 8 bf16]
//   where lane l consumes point (t*32 + (l&31)), elems (l>>5)*8 .. +8.
// XCD-SWIZZLED 1-D launch (256 blocks): blocks packing chunk cy run on
// XCD cy%8 (linear id % 8), matching knn_mfma's placement, so the chunk is
// resident in that XCD's L2 when knn_mfma's staging reads it.
// ---------------------------------------------------------------------------
__global__ __launch_bounds__(256) void pack_data(const float* __restrict__ data,
                                                 unsigned short* __restrict__ Ppk,
                                                 float* __restrict__ nhf) {
    // lb = (cy%8) + 8*(q4 + 4*(cy/8));  bijective over 256 blocks.
    const int lb  = blockIdx.x;
    const int xcd = lb & 7;
    const int r   = lb >> 3;       // [0,32)
    const int q4  = r & 3;         // quarter-chunk (256 pts)
    const int cg  = r >> 2;        // [0,8)
    const int cy  = xcd + 8 * cg;  // chunk [0,64)
    const int p   = cy * CP + q4 * 256 + threadIdx.x;

    const float4* r4 = (const float4*)(data + (size_t)p * D);
    float4 a = r4[0], b = r4[1], c = r4[2], e = r4[3];
    float v[16] = {a.x, a.y, a.z, a.w, b.x, b.y, b.z, b.w,
                   c.x, c.y, c.z, c.w, e.x, e.y, e.z, e.w};
    unsigned short hi[16], lo[16];
    float n = 0.f;
#pragma unroll
    for (int k = 0; k < 16; ++k) {
        n = fmaf(v[k], v[k], n);
        unsigned short h = f2bf(v[k]);
        hi[k] = h;
        lo[k] = f2bf(v[k] - bf2f(h));   // exact residual, rounded to bf16
    }
    const int t  = p >> 5;        // tile
    const int cc = p & 31;        // point-in-tile == output column == lane&31
    unsigned short* tb = Ppk + (size_t)t * 1024;
    const uint4* h4 = (const uint4*)hi;
    const uint4* l4 = (const uint4*)lo;
    *(uint4*)(tb +        cc * 8) = h4[0];   // hi, half 0 lane (cc)
    *(uint4*)(tb + 256 +  cc * 8) = h4[1];   // hi, half 1 lane (32+cc)
    *(uint4*)(tb + 512 +  cc * 8) = l4[0];   // lo, half 0
    *(uint4*)(tb + 768 +  cc * 8) = l4[1];   // lo, half 1
    nhf[p] = -0.5f * n;
}

// ---------------------------------------------------------------------------
// Main kernel: per wave, 64 queries (2 q-sets of 32) x one 1024-point chunk.
//   best[q] = max_p ( x_q . p - 0.5*||p||^2 )   (argmin dist2 == argmax this)
// ROUND 7b: LDS STAGING, vanilla constructs only (R7's global_load_lds +
// 65.5 KiB static LDS variant never benched — container failure; this
// version removes both risk constructs while testing the same theory).
// All 4 waves of a block consume the SAME 64 KiB chunk; previously each wave
// pulled it through the vector path as 96 latency-exposed global loads (R3
// counters: ~1400 idle cyc per wait — MfmaUtil 8%, VALUBusy 18%, HBM 4%).
// Now the block stages the chunk ONCE: 16 coalesced iterations of
// global uint4 load -> ds_write_b128 (compiler pipelines with counted
// vmcnt), the 32 per-tile norms are hoisted into registers in one burst,
// one __syncthreads, then the MFMA loop reads ONLY LDS (ds_read_b128
// ~12 cyc, standard lane-contiguous pattern). LDS byte layout identical to
// the global fragment-major layout. LDS = exactly 64 KiB -> 2 blocks/CU.
// XCD-SWIZZLED 1-D launch (512 blocks): all 8 q-slice blocks of chunk cy on
// XCD cy%8 so staging reads hit the L2 lines pack_data wrote.
// Per 32-pt tile per q-set: 3x mfma_f32_32x32x16_bf16 (hi*hi + lo*hi +
// hi*lo), C seeded with -0.5*||p||^2; 4 independent accumulator chains;
// per-pair epilogue 16x v_max3_f32 per q-set.
// C/D: col = lane&31, row = (reg&3) + 8*(reg>>2) + 4*(lane>>5)  [m74/m101].
// ---------------------------------------------------------------------------
__global__ __launch_bounds__(256, 2) void knn_mfma(const float* __restrict__ x,
                                                   const unsigned short* __restrict__ Ppk,
                                                   const float* __restrict__ nhf,
                                                   float* __restrict__ part) {
    // lb = (cy%8) + 8*(qx + 8*(cy/8));  bijective over 512 blocks.
    const int lb  = blockIdx.x;
    const int xcd = lb & 7;
    const int rr  = lb >> 3;       // [0,64)
    const int qx  = rr & 7;        // q-slice [0,8)
    const int cg  = rr >> 3;       // [0,8)
    const int cy  = xcd + 8 * cg;  // chunk [0,64)

    const int tid  = threadIdx.x;
    const int w    = tid >> 6;
    const int l    = tid & 63;
    const int half = l >> 5;
    const int n31  = l & 31;
    const int qbase = qx * 256 + w * 64;   // 4 waves x 64 queries
    const int pbase = cy * CP;

    __shared__ __align__(16) unsigned short sP[32768];  // exactly 64 KiB

    // ---- stage chunk into LDS: 16 coalesced copies (4 KiB/iter/block) ----
    const char* gC = (const char*)Ppk + (size_t)cy * 65536;  // chunk base
    char*       lC = (char*)sP;
#pragma unroll
    for (int i = 0; i < 16; ++i) {
        const int off = i * 4096 + tid * 16;
        uint4 v = *(const uint4*)(gC + off);
        *(uint4*)(lC + off) = v;
    }

    // ---- hoist all 32 per-tile norms into registers (one load burst) ----
    const float* np = nhf + pbase + n31;
    float nv[32];
#pragma unroll
    for (int t = 0; t < 32; ++t) nv[t] = np[t * 32];

    // ---- A fragments (hi/lo bf16) for both q-sets ----
    bf16x8 axh0, axl0, axh1, axl1;
    {
        const float* xr0 = x + (size_t)(qbase + n31) * D + half * 8;
        float4 a0 = *(const float4*)xr0;
        float4 a1 = *(const float4*)(xr0 + 4);
        const float xv0[8] = {a0.x, a0.y, a0.z, a0.w, a1.x, a1.y, a1.z, a1.w};
#pragma unroll
        for (int k = 0; k < 8; ++k) {
            unsigned short h = f2bf(xv0[k]);
            axh0[k] = (short)h;
            axl0[k] = (short)f2bf(xv0[k] - bf2f(h));
        }
        const float* xr1 = x + (size_t)(qbase + 32 + n31) * D + half * 8;
        float4 b0 = *(const float4*)xr1;
        float4 b1 = *(const float4*)(xr1 + 4);
        const float xv1[8] = {b0.x, b0.y, b0.z, b0.w, b1.x, b1.y, b1.z, b1.w};
#pragma unroll
        for (int k = 0; k < 8; ++k) {
            unsigned short h = f2bf(xv1[k]);
            axh1[k] = (short)h;
            axl1[k] = (short)f2bf(xv1[k] - bf2f(h));
        }
    }

    __syncthreads();   // staging writes visible to all waves

    // LDS read pointers: byte layout identical to global fragment-major.
    const unsigned short* lp = sP + l * 8;
#define LDH(t) (*(const bf16x8*)(lp + (size_t)(t) * 1024))
#define LDL(t) (*(const bf16x8*)(lp + (size_t)(t) * 1024 + 512))

    f32x16 rbest0, rbest1;
#pragma unroll
    for (int r = 0; r < 16; ++r) { rbest0[r] = -FLT_MAX; rbest1[r] = -FLT_MAX; }

    auto compute_pair = [&](bf16x8 h0, bf16x8 l0, float n0,
                            bf16x8 h1, bf16x8 l1, float n1) {
        f32x16 c00, c01, c10, c11;   // c[qset][tile]
#pragma unroll
        for (int r = 0; r < 16; ++r) {
            c00[r] = n0; c01[r] = n1; c10[r] = n0; c11[r] = n1;
        }
        // 4 independent accumulator chains, 3 MFMAs deep each.
        c00 = __builtin_amdgcn_mfma_f32_32x32x16_bf16(axh0, h0, c00, 0, 0, 0);
        c01 = __builtin_amdgcn_mfma_f32_32x32x16_bf16(axh0, h1, c01, 0, 0, 0);
        c10 = __builtin_amdgcn_mfma_f32_32x32x16_bf16(axh1, h0, c10, 0, 0, 0);
        c11 = __builtin_amdgcn_mfma_f32_32x32x16_bf16(axh1, h1, c11, 0, 0, 0);
        c00 = __builtin_amdgcn_mfma_f32_32x32x16_bf16(axl0, h0, c00, 0, 0, 0);
        c01 = __builtin_amdgcn_mfma_f32_32x32x16_bf16(axl0, h1, c01, 0, 0, 0);
        c10 = __builtin_amdgcn_mfma_f32_32x32x16_bf16(axl1, h0, c10, 0, 0, 0);
        c11 = __builtin_amdgcn_mfma_f32_32x32x16_bf16(axl1, h1, c11, 0, 0, 0);
        c00 = __builtin_amdgcn_mfma_f32_32x32x16_bf16(axh0, l0, c00, 0, 0, 0);
        c01 = __builtin_amdgcn_mfma_f32_32x32x16_bf16(axh0, l1, c01, 0, 0, 0);
        c10 = __builtin_amdgcn_mfma_f32_32x32x16_bf16(axh1, l0, c10, 0, 0, 0);
        c11 = __builtin_amdgcn_mfma_f32_32x32x16_bf16(axh1, l1, c11, 0, 0, 0);
#pragma unroll
        for (int r = 0; r < 16; ++r) {
            rbest0[r] = fmaxf(rbest0[r], fmaxf(c00[r], c01[r]));  // -> v_max3_f32
            rbest1[r] = fmaxf(rbest1[r], fmaxf(c10[r], c11[r]));
        }
    };

    // Pairs of tiles straight from LDS; compiler pipelines ds_reads with
    // counted lgkmcnt waits across iterations.
    for (int p = 0; p < TPW; p += 2) {
        compute_pair(LDH(p),     LDL(p),     nv[p],
                     LDH(p + 1), LDL(p + 1), nv[p + 1]);
    }
#undef LDH
#undef LDL

    // max over the 32 point-columns (lanes within each half)
#pragma unroll
    for (int r = 0; r < 16; ++r) {
        float v0 = rbest0[r];
        v0 = fmaxf(v0, __shfl_xor(v0, 1, 32));
        v0 = fmaxf(v0, __shfl_xor(v0, 2, 32));
        v0 = fmaxf(v0, __shfl_xor(v0, 4, 32));
        v0 = fmaxf(v0, __shfl_xor(v0, 8, 32));
        v0 = fmaxf(v0, __shfl_xor(v0, 16, 32));
        rbest0[r] = v0;
        float v1 = rbest1[r];
        v1 = fmaxf(v1, __shfl_xor(v1, 1, 32));
        v1 = fmaxf(v1, __shfl_xor(v1, 2, 32));
        v1 = fmaxf(v1, __shfl_xor(v1, 4, 32));
        v1 = fmaxf(v1, __shfl_xor(v1, 8, 32));
        v1 = fmaxf(v1, __shfl_xor(v1, 16, 32));
        rbest1[r] = v1;
    }
    if (n31 == 0) {
        float* pp = part + (size_t)cy * NQ + qbase + 4 * half;
#pragma unroll
        for (int r = 0; r < 16; ++r) pp[(r & 3) + 8 * (r >> 2)] = rbest0[r];
        pp += 32;
#pragma unroll
        for (int r = 0; r < 16; ++r) pp[(r & 3) + 8 * (r >> 2)] = rbest1[r];
    }
}

// ---------------------------------------------------------------------------
// Final: reduce SCH chunks, dist2 = ||x||^2 - 2*best, bump.
// ---------------------------------------------------------------------------
__global__ __launch_bounds__(256) void knn_final(const float* __restrict__ x,
                                                 const float* __restrict__ part,
                                                 float* __restrict__ out) {
    const int q = blockIdx.x * 256 + threadIdx.x;
    const float4* xr = (const float4*)(x + (size_t)q * D);
    float4 a = xr[0], b = xr[1], c = xr[2], e = xr[3];
    float x2 = a.x * a.x;
    x2 = fmaf(a.y, a.y, x2); x2 = fmaf(a.z, a.z, x2); x2 = fmaf(a.w, a.w, x2);
    x2 = fmaf(b.x, b.x, x2); x2 = fmaf(b.y, b.y, x2); x2 = fmaf(b.z, b.z, x2); x2 = fmaf(b.w, b.w, x2);
    x2 = fmaf(c.x, c.x, x2); x2 = fmaf(c.y, c.y, x2); x2 = fmaf(c.z, c.z, x2); x2 = fmaf(c.w, c.w, x2);
    x2 = fmaf(e.x, e.x, x2); x2 = fmaf(e.y, e.y, x2); x2 = fmaf(e.z, e.z, x2); x2 = fmaf(e.w, e.w, x2);

    float mbest = -FLT_MAX;
#pragma unroll
    for (int cI = 0; cI < SCH; ++cI) mbest = fmaxf(mbest, part[(size_t)cI * NQ + q]);

    float nn2  = fmaxf(fmaf(-2.f, mbest, x2), 0.f);
    float dist = sqrtf(fmaxf(nn2, 1e-12f));
    float bump = 0.f;
    if (dist < 2.0f) {                      // RADIUS = 2
        float denom = dist * dist - 4.0f;   // d^2 - r^2
        bump = expf(1.0f / denom + 0.25f);  // DECAY/denom + DECAY/r^2
    }
    out[q] = bump;
}

// ===========================================================================
// Fallback (fp32 scalar-pipe path) if workspace is too small for MFMA path.
// ===========================================================================
__global__ __launch_bounds__(256) void neg_half_norms(const float* __restrict__ data,
                                                      float* __restrict__ nhn) {
    const int p = blockIdx.x * 256 + threadIdx.x;
    const float4* r = (const float4*)(data + (size_t)p * D);
    float4 a = r[0], b = r[1], c = r[2], e = r[3];
    float n = a.x * a.x;
    n = fmaf(a.y, a.y, n); n = fmaf(a.z, a.z, n); n = fmaf(a.w, a.w, n);
    n = fmaf(b.x, b.x, n); n = fmaf(b.y, b.y, n); n = fmaf(b.z, b.z, n); n = fmaf(b.w, b.w, n);
    n = fmaf(c.x, c.x, n); n = fmaf(c.y, c.y, n); n = fmaf(c.z, c.z, n); n = fmaf(c.w, c.w, n);
    n = fmaf(e.x, e.x, n); n = fmaf(e.y, e.y, n); n = fmaf(e.z, e.z, n); n = fmaf(e.w, e.w, n);
    nhn[p] = -0.5f * n;
}

__global__ __launch_bounds__(256) void knn_partial_fb(const float* __restrict__ x,
                                                      const float* __restrict__ data,
                                                      const float* __restrict__ nhn,
                                                      float* __restrict__ part, int cp) {
    const int q     = blockIdx.x * 256 + threadIdx.x;
    const int pbase = blockIdx.y * cp;
    const float4* xr = (const float4*)(x + (size_t)q * D);
    const float4 xa = xr[0], xb = xr[1], xc = xr[2], xd = xr[3];
    const float* dp = data + (size_t)pbase * D;
    const float* np = nhn + pbase;
    float best = -FLT_MAX;
    for (int i = 0; i < cp; i += 4) {
#pragma unroll
        for (int j = 0; j < 4; ++j) {
            const float* r  = dp + (size_t)(i + j) * D;
            const float  hn = np[i + j];
            float ca = xa.x * r[0];
            ca = fmaf(xa.y, r[1], ca);  ca = fmaf(xa.z, r[2], ca);  ca = fmaf(xa.w, r[3], ca);
            ca = fmaf(xb.x, r[4], ca);  ca = fmaf(xb.y, r[5], ca);  ca = fmaf(xb.z, r[6], ca);
            ca = fmaf(xb.w, r[7], ca);
            float cb = fmaf(xc.x, r[8], hn);
            cb = fmaf(xc.y, r[9],  cb); cb = fmaf(xc.z, r[10], cb); cb = fmaf(xc.w, r[11], cb);
            cb = fmaf(xd.x, r[12], cb); cb = fmaf(xd.y, r[13], cb); cb = fmaf(xd.z, r[14], cb);
            cb = fmaf(xd.w, r[15], cb);
            best = fmaxf(best, ca + cb);
        }
    }
    part[(size_t)blockIdx.y * NQ + q] = best;
}

__global__ __launch_bounds__(256) void knn_final_fb(const float* __restrict__ x,
                                                    const float* __restrict__ part,
                                                    float* __restrict__ out, int S) {
    const int q = blockIdx.x * 256 + threadIdx.x;
    const float4* xr = (const float4*)(x + (size_t)q * D);
    float4 a = xr[0], b = xr[1], c = xr[2], e = xr[3];
    float x2 = a.x * a.x;
    x2 = fmaf(a.y, a.y, x2); x2 = fmaf(a.z, a.z, x2); x2 = fmaf(a.w, a.w, x2);
    x2 = fmaf(b.x, b.x, x2); x2 = fmaf(b.y, b.y, x2); x2 = fmaf(b.z, b.z, x2); x2 = fmaf(b.w, b.w, x2);
    x2 = fmaf(c.x, c.x, x2); x2 = fmaf(c.y, c.y, x2); x2 = fmaf(c.z, c.z, x2); x2 = fmaf(c.w, c.w, x2);
    x2 = fmaf(e.x, e.x, x2); x2 = fmaf(e.y, e.y, x2); x2 = fmaf(e.z, e.z, x2); x2 = fmaf(e.w, e.w, x2);
    float mb = -FLT_MAX;
    for (int cI = 0; cI < S; ++cI) mb = fmaxf(mb, part[(size_t)cI * NQ + q]);
    float nn2  = fmaxf(fmaf(-2.f, mb, x2), 0.f);
    float dist = sqrtf(fmaxf(nn2, 1e-12f));
    float bump = 0.f;
    if (dist < 2.0f) {
        float denom = dist * dist - 4.0f;
        bump = expf(1.0f / denom + 0.25f);
    }
    out[q] = bump;
}

extern "C" void kernel_launch(void* const* d_in, const int* in_sizes, int n_in,
                              void* d_out, int out_size, void* d_ws, size_t ws_size,
                              hipStream_t stream) {
    const float* x    = (const float*)d_in[0];   // [2048,16] fp32
    const float* data = (const float*)d_in[1];   // [65536,16] fp32
    float* out = (float*)d_out;                  // [2048] fp32

    // ws layout (bytes):
    //   Ppk  [0, 4 MiB)          ND/32 tiles * 1024 shorts (fragment-major)
    //   nhf  [4 MiB, +256 KiB)   ND fp32
    //   part [+512 KiB)          SCH*NQ fp32
    const size_t off_nhf  = (size_t)ND * 32 * 2;             // 4194304
    const size_t off_part = off_nhf + (size_t)ND * 4;        // 4456448
    const size_t needed   = off_part + (size_t)SCH * NQ * 4; // 4980736

    if (ws_size >= needed) {
        unsigned short* Ppk = (unsigned short*)d_ws;
        float* nhf  = (float*)((char*)d_ws + off_nhf);
        float* part = (float*)((char*)d_ws + off_part);

        pack_data<<<ND / 256, 256, 0, stream>>>(data, Ppk, nhf);
        knn_mfma<<<8 * SCH, 256, 0, stream>>>(x, Ppk, nhf, part);
        knn_final<<<NQ / 256, 256, 0, stream>>>(x, part, out);
    } else {
        int S = 32;
        while (S > 1 && (size_t)(ND + S * NQ) * sizeof(float) > ws_size) S >>= 1;
        const int cp = ND / S;
        float* nhn  = (float*)d_ws;
        float* part = (float*)d_ws + ND;
        neg_half_norms<<<ND / 256, 256, 0, stream>>>(data, nhn);
        knn_partial_fb<<<dim3(NQ / 256, S), 256, 0, stream>>>(x, data, nhn, part, cp);
        knn_final_fb<<<NQ / 256, 256, 0, stream>>>(x, part, out, S);
    }
}